// Round 8
// baseline (322.666 us; speedup 1.0000x reference)
//
#include <hip/hip_runtime.h>
#include <hip/hip_bf16.h>

// Problem dims (fixed)
#define B_SZ 2
#define L_SEQ 512
#define D_MODEL 256
#define D_STATE 128
#define D_CONV 4
#define D_INNER 1024
#define DT_RANK 16
#define N_HEADS 8
#define DK 32
#define D_FF 1024
#define R_TOT (B_SZ * L_SEQ)   // 1024 rows
#define DBL_LD (DT_RANK + 2 * D_STATE)  // 272
#define NSEG 16
#define SEGL 32   // L_SEQ / NSEG
#define DPB 4     // d-channels per scan block (B/C register reuse)

typedef __hip_bfloat16 bf16;
typedef __attribute__((ext_vector_type(8))) short short8;   // 8 bf16 = 4 VGPR
typedef __attribute__((ext_vector_type(4))) float floatx4;

// Fast transcendentals (native v_exp/v_log/v_rcp; 1-4 ULP, self-damping in scan)
__device__ inline float fexp(float x) { return __expf(x); }
__device__ inline float fexp2(float x) { return __builtin_amdgcn_exp2f(x); }
__device__ inline float frcp(float x) { return __builtin_amdgcn_rcpf(x); }
__device__ inline float silu_f(float x) { return x * frcp(1.f + fexp(-x)); }
__device__ inline float softplus_f(float x) { return (x > 20.f) ? x : __logf(1.f + fexp(x)); }
__device__ inline float bf2f(unsigned short u) { return __uint_as_float(((unsigned)u) << 16); }
__device__ inline unsigned short f2bfbits(float x) {
    bf16 h = __float2bfloat16(x);
    return *reinterpret_cast<unsigned short*>(&h);
}

__device__ inline float swz_xor16(float x) {
    return __int_as_float(__builtin_amdgcn_ds_swizzle(__float_as_int(x), 0x401F));
}

// ---------------------------------------------------------------------------
// Dispatch 0: pack (mem + 9 weights f32->bf16, vectorized x4) + LN1 +
// zero-fill of h1 (atomic target), out, dbl.
// ---------------------------------------------------------------------------
#define S_MEM 262144
#define S_INW 524288
#define S_XPW 278528
#define S_OPW 262144
#define S_WQ  65536
#define S_WK  65536
#define S_WV  65536
#define S_WO  65536
#define S_W1  262144
#define S_W2  262144
#define S_TOT (S_MEM+S_INW+S_XPW+S_OPW+S_WQ+S_WK+S_WV+S_WO+S_W1+S_W2)
#define PACK_BLKS (S_TOT / 4 / 256)       // 2064 (exact)
#define Z1_F4 (R_TOT * D_MODEL / 4)       // h1 float4 count
#define Z2_F4 (R_TOT * D_MODEL / 4)       // out float4 count
#define Z3_F4 (R_TOT * DBL_LD / 4)        // dbl float4 count
#define ZERO_BLKS ((Z1_F4 + Z2_F4 + Z3_F4 + 255) / 256)

__global__ __launch_bounds__(256) void pack_ln1(
    const float* __restrict__ s0, const float* __restrict__ s1,
    const float* __restrict__ s2, const float* __restrict__ s3,
    const float* __restrict__ s4, const float* __restrict__ s5,
    const float* __restrict__ s6, const float* __restrict__ s7,
    const float* __restrict__ s8, const float* __restrict__ s9,
    bf16* __restrict__ dst,
    const float* __restrict__ X, const float* __restrict__ a,
    const float* __restrict__ bvec, bf16* __restrict__ ln1b,
    float* __restrict__ zero1, float* __restrict__ zero2,
    float* __restrict__ zero3)
{
    __shared__ float r1[256], r2[256];
    if (blockIdx.x < PACK_BLKS) {
        const long e0 = ((long)blockIdx.x * 256 + threadIdx.x) * 4;
        const long off[11] = {0, S_MEM, S_MEM+S_INW, S_MEM+S_INW+S_XPW,
            S_MEM+S_INW+S_XPW+S_OPW, S_MEM+S_INW+S_XPW+S_OPW+S_WQ,
            S_MEM+S_INW+S_XPW+S_OPW+S_WQ+S_WK,
            S_MEM+S_INW+S_XPW+S_OPW+S_WQ+S_WK+S_WV,
            S_MEM+S_INW+S_XPW+S_OPW+S_WQ+S_WK+S_WV+S_WO,
            S_MEM+S_INW+S_XPW+S_OPW+S_WQ+S_WK+S_WV+S_WO+S_W1, S_TOT};
        const float* srcs[10] = {s0,s1,s2,s3,s4,s5,s6,s7,s8,s9};
        int seg = 0;
#pragma unroll
        for (int k = 1; k < 10; ++k) if (e0 >= off[k]) seg = k;
        const float4 v = *(const float4*)&srcs[seg][e0 - off[seg]];
        ushort4 pk;
        pk.x = f2bfbits(v.x); pk.y = f2bfbits(v.y);
        pk.z = f2bfbits(v.z); pk.w = f2bfbits(v.w);
        *reinterpret_cast<ushort4*>(dst + e0) = pk;
    } else if (blockIdx.x < PACK_BLKS + R_TOT) {
        const int row = blockIdx.x - PACK_BLKS;
        const int t = threadIdx.x;
        const float v = X[(long)row * D_MODEL + t];
        r1[t] = v;
        r2[t] = v * v;
        __syncthreads();
        for (int s = 128; s > 0; s >>= 1) {
            if (t < s) { r1[t] += r1[t + s]; r2[t] += r2[t + s]; }
            __syncthreads();
        }
        const float mean = r1[0] * (1.f / 256.f);
        const float var = (r2[0] - 256.f * mean * mean) * (1.f / 255.f);
        const float sd = sqrtf(fmaxf(var, 0.f));
        const float o = a[t] * (v - mean) / (sd + 1e-6f) + bvec[t];
        ln1b[(long)row * D_MODEL + t] = __float2bfloat16(o);
    } else {
        const long i4 = (long)(blockIdx.x - PACK_BLKS - R_TOT) * 256 + threadIdx.x;
        const float4 z = {0.f, 0.f, 0.f, 0.f};
        if (i4 < Z1_F4)                      *(float4*)&zero1[i4 * 4] = z;
        else if (i4 < Z1_F4 + Z2_F4)          *(float4*)&zero2[(i4 - Z1_F4) * 4] = z;
        else if (i4 < Z1_F4 + Z2_F4 + Z3_F4)  *(float4*)&zero3[(i4 - Z1_F4 - Z2_F4) * 4] = z;
    }
}

// ---------------------------------------------------------------------------
// xz GEMM + k/v GEMM merged (all full-K=256, bf16 out).  Grid (40, 16):
// x<32: xz tile (N=2048); x>=32: e=x-32, which=e>>2 (k/v), bn=(e&3)*64.
// k/v moved here from the xproj dispatch -- depends only on dispatch 0.
// ---------------------------------------------------------------------------
__global__ __launch_bounds__(256) void xz_kv_gemm(
    const bf16* __restrict__ ln1b, const bf16* __restrict__ INWb,
    bf16* __restrict__ xzb,
    const bf16* __restrict__ memb, const bf16* __restrict__ WKb,
    const bf16* __restrict__ WVb,
    const float* __restrict__ WKB, const float* __restrict__ WVB,
    bf16* __restrict__ kbb, bf16* __restrict__ vbb)
{
    const int wave = threadIdx.x >> 6;
    const int lane = threadIdx.x & 63;
    const int row16 = lane & 15;
    const int quad  = lane >> 4;
    const int bm = blockIdx.y * 64 + wave * 16;
    const int x = blockIdx.x;

    const bf16* A; const bf16* W; const float* bias; bf16* O;
    int bn, ldc;
    if (x < 32) {
        A = ln1b; W = INWb; bias = nullptr; O = xzb;
        bn = x * 64; ldc = 2 * D_INNER;
    } else {
        const int e = x - 32;
        const int which = e >> 2;
        A = memb; W = which ? WVb : WKb; bias = which ? WVB : WKB;
        O = which ? vbb : kbb;
        bn = (e & 3) * 64; ldc = D_MODEL;
    }

    floatx4 acc[4];
#pragma unroll
    for (int t = 0; t < 4; ++t) acc[t] = (floatx4){0.f, 0.f, 0.f, 0.f};

    const long arow = (long)(bm + row16) * D_MODEL;
    for (int k0 = 0; k0 < D_MODEL; k0 += 32) {
        const short8 av = *(const short8*)(A + arow + k0 + quad * 8);
#pragma unroll
        for (int t = 0; t < 4; ++t) {
            const int gn = bn + t * 16 + row16;
            const short8 bv = *(const short8*)(W + (long)gn * D_MODEL + k0 + quad * 8);
            acc[t] = __builtin_amdgcn_mfma_f32_16x16x32_bf16(av, bv, acc[t], 0, 0, 0);
        }
    }

#pragma unroll
    for (int t = 0; t < 4; ++t) {
        const int gn = bn + t * 16 + row16;
        const float bs = bias ? bias[gn] : 0.f;
#pragma unroll
        for (int r = 0; r < 4; ++r) {
            const int gm = bm + quad * 4 + r;
            O[(long)gm * ldc + gn] = __float2bfloat16(acc[t][r] + bs);
        }
    }
}

// ---------------------------------------------------------------------------
// MFMA GEMM: C = epi(A @ W^T + bias)(+res), bf16 inputs, f32/bf16 out. (w1)
// ---------------------------------------------------------------------------
template <int EPI>
__global__ __launch_bounds__(256) void mfma_gemm(
    const bf16* __restrict__ A, const bf16* __restrict__ W, int K,
    float* __restrict__ C, bf16* __restrict__ Cb, int ldc,
    const float* __restrict__ bias, const float* __restrict__ res,
    int M, int N)
{
    const int wave = threadIdx.x >> 6;
    const int lane = threadIdx.x & 63;
    const int row16 = lane & 15;
    const int quad  = lane >> 4;
    const int bm = blockIdx.y * 64 + wave * 16;
    const int bn = blockIdx.x * 64;

    floatx4 acc[4];
#pragma unroll
    for (int t = 0; t < 4; ++t) acc[t] = (floatx4){0.f, 0.f, 0.f, 0.f};

    const long arow = (long)(bm + row16) * K;
    for (int k0 = 0; k0 < K; k0 += 32) {
        const short8 av = *(const short8*)(A + arow + k0 + quad * 8);
#pragma unroll
        for (int t = 0; t < 4; ++t) {
            const int gn = bn + t * 16 + row16;
            short8 bv = {0,0,0,0,0,0,0,0};
            if (gn < N) bv = *(const short8*)(W + (long)gn * K + k0 + quad * 8);
            acc[t] = __builtin_amdgcn_mfma_f32_16x16x32_bf16(av, bv, acc[t], 0, 0, 0);
        }
    }

#pragma unroll
    for (int t = 0; t < 4; ++t) {
        const int gn = bn + t * 16 + row16;
        if (gn >= N) continue;
        const float bs = bias ? bias[gn] : 0.f;
#pragma unroll
        for (int r = 0; r < 4; ++r) {
            const int gm = bm + quad * 4 + r;
            float v = acc[t][r] + bs;
            if (EPI == 1) v = fmaxf(v, 0.f);
            const long ci = (long)gm * ldc + gn;
            if (res) v += res[ci];
            if (C)  C[ci] = v;
            if (Cb) Cb[ci] = __float2bfloat16(v);
        }
    }
}

// ---------------------------------------------------------------------------
// Split-K MFMA GEMM (out_proj, w2): atomicAdd into pre-zeroed f32 C.
// ---------------------------------------------------------------------------
template <int SK>
__global__ __launch_bounds__(256) void splitk_gemm(
    const bf16* __restrict__ A, const bf16* __restrict__ W, int K,
    float* __restrict__ C, int ldc,
    const float* __restrict__ bias, const float* __restrict__ res,
    int M, int N)
{
    const int wave = threadIdx.x >> 6;
    const int lane = threadIdx.x & 63;
    const int row16 = lane & 15;
    const int quad  = lane >> 4;
    const int bm = blockIdx.y * 64 + wave * 16;
    const int bn = blockIdx.x * 64;
    const int kz = blockIdx.z;
    const int ksl = K / SK;
    const int kbeg = kz * ksl;

    floatx4 acc[4];
#pragma unroll
    for (int t = 0; t < 4; ++t) acc[t] = (floatx4){0.f, 0.f, 0.f, 0.f};

    const long arow = (long)(bm + row16) * K;
    for (int k0 = kbeg; k0 < kbeg + ksl; k0 += 32) {
        const short8 av = *(const short8*)(A + arow + k0 + quad * 8);
#pragma unroll
        for (int t = 0; t < 4; ++t) {
            const int gn = bn + t * 16 + row16;
            short8 bv = {0,0,0,0,0,0,0,0};
            if (gn < N) bv = *(const short8*)(W + (long)gn * K + k0 + quad * 8);
            acc[t] = __builtin_amdgcn_mfma_f32_16x16x32_bf16(av, bv, acc[t], 0, 0, 0);
        }
    }

#pragma unroll
    for (int t = 0; t < 4; ++t) {
        const int gn = bn + t * 16 + row16;
        if (gn >= N) continue;
        const float bs = (kz == 0 && bias) ? bias[gn] : 0.f;
#pragma unroll
        for (int r = 0; r < 4; ++r) {
            const int gm = bm + quad * 4 + r;
            float v = acc[t][r] + bs;
            const long ci = (long)gm * ldc + gn;
            if (kz == 0 && res) v += res[ci];
            atomicAdd(&C[ci], v);
        }
    }
}

// ---------------------------------------------------------------------------
// x_proj only (split-K=4, atomics into pre-zeroed dbl): grid (5, 16, 4).
// ---------------------------------------------------------------------------
__global__ __launch_bounds__(256) void xproj_gemm(
    const bf16* __restrict__ ub, const bf16* __restrict__ XPWb,
    float* __restrict__ dbl)
{
    const int wave = threadIdx.x >> 6;
    const int lane = threadIdx.x & 63;
    const int row16 = lane & 15;
    const int quad  = lane >> 4;
    const int bm = blockIdx.y * 64 + wave * 16;
    const int bn = blockIdx.x * 64;
    const int z = blockIdx.z;
    const int ksl = D_INNER / 4, kbeg = z * ksl;

    floatx4 acc[4];
#pragma unroll
    for (int t = 0; t < 4; ++t) acc[t] = (floatx4){0.f, 0.f, 0.f, 0.f};

    const long arow = (long)(bm + row16) * D_INNER;
    for (int k0 = kbeg; k0 < kbeg + ksl; k0 += 32) {
        const short8 av = *(const short8*)(ub + arow + k0 + quad * 8);
#pragma unroll
        for (int t = 0; t < 4; ++t) {
            const int gn = bn + t * 16 + row16;
            short8 bv = {0,0,0,0,0,0,0,0};
            if (gn < DBL_LD) bv = *(const short8*)(XPWb + (long)gn * D_INNER + k0 + quad * 8);
            acc[t] = __builtin_amdgcn_mfma_f32_16x16x32_bf16(av, bv, acc[t], 0, 0, 0);
        }
    }

#pragma unroll
    for (int t = 0; t < 4; ++t) {
        const int gn = bn + t * 16 + row16;
        if (gn >= DBL_LD) continue;
#pragma unroll
        for (int r = 0; r < 4; ++r) {
            const int gm = bm + quad * 4 + r;
            atomicAdd(&dbl[(long)gm * DBL_LD + gn], acc[t][r]);
        }
    }
}

// ---------------------------------------------------------------------------
// gemm16_ln: wo (K=256) + fused LN3. grid = M/16 blocks.
// ---------------------------------------------------------------------------
__global__ __launch_bounds__(256) void gemm16_ln(
    const bf16* __restrict__ A, const bf16* __restrict__ W, int K,
    const float* __restrict__ bias, const float* __restrict__ res,
    float* __restrict__ Cf,
    const float* __restrict__ lna, const float* __restrict__ lnb,
    bf16* __restrict__ lnout)
{
    __shared__ float tile[16][264];
    __shared__ float red1[16][16];
    __shared__ float red2[16][16];
    const int w = threadIdx.x >> 6;
    const int lane = threadIdx.x & 63;
    const int row16 = lane & 15;
    const int quad  = lane >> 4;
    const int bm = blockIdx.x * 16;

    floatx4 acc[4];
#pragma unroll
    for (int t = 0; t < 4; ++t) acc[t] = (floatx4){0.f, 0.f, 0.f, 0.f};

    const long arow = (long)(bm + row16) * K;
    for (int k0 = 0; k0 < K; k0 += 32) {
        const short8 av = *(const short8*)(A + arow + k0 + quad * 8);
#pragma unroll
        for (int t = 0; t < 4; ++t) {
            const int gn = w * 64 + t * 16 + row16;
            const short8 bv = *(const short8*)(W + (long)gn * K + k0 + quad * 8);
            acc[t] = __builtin_amdgcn_mfma_f32_16x16x32_bf16(av, bv, acc[t], 0, 0, 0);
        }
    }

#pragma unroll
    for (int t = 0; t < 4; ++t) {
        const int gn = w * 64 + t * 16 + row16;
        const float bs = bias ? bias[gn] : 0.f;
#pragma unroll
        for (int r = 0; r < 4; ++r) {
            const int gm = bm + quad * 4 + r;
            float v = acc[t][r] + bs;
            const long ci = (long)gm * D_MODEL + gn;
            if (res) v += res[ci];
            Cf[ci] = v;
            tile[quad * 4 + r][gn] = v;
        }
    }
    __syncthreads();

    const int r = threadIdx.x >> 4;
    const int g = threadIdx.x & 15;
    float s = 0.f, q = 0.f;
#pragma unroll
    for (int i = 0; i < 16; ++i) {
        const float x = tile[r][g * 16 + i];
        s += x; q += x * x;
    }
    red1[r][g] = s; red2[r][g] = q;
    __syncthreads();
    float ts = 0.f, tq = 0.f;
#pragma unroll
    for (int i = 0; i < 16; ++i) { ts += red1[r][i]; tq += red2[r][i]; }
    const float mean = ts * (1.f / 256.f);
    const float var = (tq - 256.f * mean * mean) * (1.f / 255.f);
    const float sd = sqrtf(fmaxf(var, 0.f));
    const long rowbase = (long)(bm + r) * D_MODEL;
#pragma unroll
    for (int i = 0; i < 16; ++i) {
        const int c = g * 16 + i;
        const float o = lna[c] * (tile[r][c] - mean) / (sd + 1e-6f) + lnb[c];
        lnout[rowbase + c] = __float2bfloat16(o);
    }
}

// ---------------------------------------------------------------------------
// Tiled causal conv(k=4)+SiLU over bf16 xz -> ub (bf16) + uT (f32 [b][d][l]).
// ---------------------------------------------------------------------------
__global__ __launch_bounds__(256) void conv_silu_T(
    const bf16* __restrict__ xz, const float* __restrict__ cw,
    const float* __restrict__ cb, bf16* __restrict__ ub, float* __restrict__ uT)
{
    __shared__ float t[64][65];
    const int db = blockIdx.x;
    const int lb = blockIdx.y;
    const int b  = blockIdx.z;
    const int tid = threadIdx.x;
    const int r  = tid >> 4;
    const int c4 = (tid & 15) * 4;
    const int d0 = db * 64 + c4;

    const float4 cb4 = *(const float4*)&cb[d0];
    float cwa[4][4];
#pragma unroll
    for (int i = 0; i < 4; ++i) {
        const float4 w = *(const float4*)&cw[(d0 + i) * 4];
        cwa[i][0] = w.x; cwa[i][1] = w.y; cwa[i][2] = w.z; cwa[i][3] = w.w;
    }

#pragma unroll
    for (int q = 0; q < 4; ++q) {
        const int ll = r + q * 16;
        const int l = lb * 64 + ll;
        float s0 = cb4.x, s1 = cb4.y, s2 = cb4.z, s3 = cb4.w;
#pragma unroll
        for (int k = 0; k < D_CONV; ++k) {
            const int ls = l - 3 + k;
            if (ls >= 0) {
                const ushort4 xv = *(const ushort4*)&xz[((long)(b * L_SEQ + ls)) * (2 * D_INNER) + d0];
                s0 = fmaf(bf2f(xv.x), cwa[0][k], s0);
                s1 = fmaf(bf2f(xv.y), cwa[1][k], s1);
                s2 = fmaf(bf2f(xv.z), cwa[2][k], s2);
                s3 = fmaf(bf2f(xv.w), cwa[3][k], s3);
            }
        }
        s0 = silu_f(s0); s1 = silu_f(s1); s2 = silu_f(s2); s3 = silu_f(s3);
        ushort4 pk;
        pk.x = f2bfbits(s0); pk.y = f2bfbits(s1);
        pk.z = f2bfbits(s2); pk.w = f2bfbits(s3);
        *reinterpret_cast<ushort4*>(ub + ((long)(b * L_SEQ + l)) * D_INNER + d0) = pk;
        t[c4 + 0][ll] = s0; t[c4 + 1][ll] = s1;
        t[c4 + 2][ll] = s2; t[c4 + 3][ll] = s3;
    }
    __syncthreads();
#pragma unroll
    for (int q = 0; q < 4; ++q) {
        const int dl = r + q * 16;
        float4 v = {t[dl][c4], t[dl][c4 + 1], t[dl][c4 + 2], t[dl][c4 + 3]};
        *(float4*)&uT[((long)(b * D_INNER + db * 64 + dl) << 9) + lb * 64 + c4] = v;
    }
}

// ---------------------------------------------------------------------------
// Fused segmented scan + GATE epilogue + ON-THE-FLY dt (v6, measured 84 us).
// ---------------------------------------------------------------------------
__global__ __launch_bounds__(1024) void scan_fused(
    const float* __restrict__ uT,
    const float* __restrict__ dbl, const float* __restrict__ A_log,
    const float* __restrict__ DTW, const float* __restrict__ DTB,
    const float* __restrict__ Dp, const bf16* __restrict__ xz,
    bf16* __restrict__ yb)
{
    const int b  = blockIdx.x >> 8;               // D_INNER/DPB = 256 blocks / b
    const int d0 = (blockIdx.x & 255) * DPB;
    const int w = threadIdx.x >> 6;               // segment 0..15
    const int lane = threadIdx.x & 63;
    const int n0 = lane * 2;

    __shared__ float Sh[NSEG][DPB][D_STATE];
    __shared__ float Ph[NSEG][DPB][D_STATE];
    __shared__ float DtS[NSEG][DPB][SEGL];        // 8 KB on-the-fly dt

    // ---- on-the-fly dt: each wave fills DtS[w] (wave-local, no barrier) --
    {
        const int dij = lane >> 4;                // 0..3
        const int ll  = (lane & 15) * 2;          // 0,2,..,30
        const int l   = w * SEGL + ll;
        const float* dr0 = dbl + (long)(b * L_SEQ + l) * DBL_LD;
        const float* dr1 = dr0 + DBL_LD;
        const float* wr  = DTW + (long)(d0 + dij) * DT_RANK;
        const float bs = DTB[d0 + dij];
        float a0 = 0.f, a1 = 0.f;
#pragma unroll
        for (int k = 0; k < DT_RANK; ++k) {
            const float wv = wr[k];
            a0 = fmaf(dr0[k], wv, a0);
            a1 = fmaf(dr1[k], wv, a1);
        }
        DtS[w][dij][ll]     = softplus_f(a0 + bs);
        DtS[w][dij][ll + 1] = softplus_f(a1 + bs);
    }

    float An0[DPB], An1[DPB];
#pragma unroll
    for (int di = 0; di < DPB; ++di) {
        An0[di] = -fexp(A_log[(long)(d0 + di) * D_STATE + n0]) * 1.44269504f;
        An1[di] = -fexp(A_log[(long)(d0 + di) * D_STATE + n0 + 1]) * 1.44269504f;
    }
    const float4 dp4 = *(const float4*)&Dp[d0];
    const float dpc[4] = {dp4.x, dp4.y, dp4.z, dp4.w};

    const float* blp = dbl + ((long)(b * L_SEQ + w * SEGL)) * DBL_LD + DT_RANK + n0;
    const float* clp = blp + D_STATE;
    const long tbase = ((long)(b * D_INNER + d0) << 9) + w * SEGL;

    if (w < NSEG - 1) {
        float h0[DPB] = {}, h1[DPB] = {}, sdt[DPB] = {};
        for (int s = 0; s < SEGL / 4; ++s) {
            float2 Bv[4];
#pragma unroll
            for (int j = 0; j < 4; ++j)
                Bv[j] = *(const float2*)(blp + (long)(s * 4 + j) * DBL_LD);
#pragma unroll
            for (int di = 0; di < DPB; ++di) {
                const float4 dt0 = *(const float4*)&DtS[w][di][s * 4];
                const float4 u0  = *(const float4*)(uT  + tbase + ((long)di << 9) + s * 4);
                const float dts[4] = {dt0.x, dt0.y, dt0.z, dt0.w};
                const float us[4]  = {u0.x, u0.y, u0.z, u0.w};
#pragma unroll
                for (int j = 0; j < 4; ++j) {
                    const float dtv = dts[j];
                    sdt[di] += dtv;
                    const float dtu = dtv * us[j];
                    h0[di] = fmaf(fexp2(dtv * An0[di]), h0[di], dtu * Bv[j].x);
                    h1[di] = fmaf(fexp2(dtv * An1[di]), h1[di], dtu * Bv[j].y);
                }
            }
        }
#pragma unroll
        for (int di = 0; di < DPB; ++di) {
            Sh[w][di][n0]     = h0[di];
            Sh[w][di][n0 + 1] = h1[di];
            Ph[w][di][n0]     = fexp2(An0[di] * sdt[di]);
            Ph[w][di][n0 + 1] = fexp2(An1[di] * sdt[di]);
        }
    }
    __syncthreads();

    float h0[DPB] = {}, h1[DPB] = {};
    for (int s = 0; s < w; ++s) {
#pragma unroll
        for (int di = 0; di < DPB; ++di) {
            h0[di] = fmaf(Ph[s][di][n0],     h0[di], Sh[s][di][n0]);
            h1[di] = fmaf(Ph[s][di][n0 + 1], h1[di], Sh[s][di][n0 + 1]);
        }
    }

    const int bpa = (lane ^ 32) << 2;      // ds_bpermute byte addr (xor-32)
    const bool lo32 = lane < 32;
    const bool b16 = (lane & 16) != 0;
    const int g = lane >> 4;               // 16-lane group owns timestep s*4+g
    const bool wl = (lane & 15) == 15;     // writer lane per group

    for (int s = 0; s < SEGL / 4; ++s) {
        float2 Bv[4], Cv[4];
#pragma unroll
        for (int j = 0; j < 4; ++j) {
            Bv[j] = *(const float2*)(blp + (long)(s * 4 + j) * DBL_LD);
            Cv[j] = *(const float2*)(clp + (long)(s * 4 + j) * DBL_LD);
        }
        float zsel[DPB];
#pragma unroll
        for (int di = 0; di < DPB; ++di) {
            const float4 dt0 = *(const float4*)&DtS[w][di][s * 4];
            const float4 u0  = *(const float4*)(uT  + tbase + ((long)di << 9) + s * 4);
            const float dts[4] = {dt0.x, dt0.y, dt0.z, dt0.w};
            const float us[4]  = {u0.x, u0.y, u0.z, u0.w};
            float yp[4];
#pragma unroll
            for (int j = 0; j < 4; ++j) {
                const float dtv = dts[j];
                const float dtu = dtv * us[j];
                h0[di] = fmaf(fexp2(dtv * An0[di]), h0[di], dtu * Bv[j].x);
                h1[di] = fmaf(fexp2(dtv * An1[di]), h1[di], dtu * Bv[j].y);
                yp[j] = fmaf(h0[di], Cv[j].x, h1[di] * Cv[j].y);
            }
            if (lane == 0) {
#pragma unroll
                for (int j = 0; j < 4; ++j)
                    yp[j] = fmaf(us[j], dpc[di], yp[j]);   // inject u*Dp once
            }
            // fold 4 -> 2 across the 32-lane halves (bpermute xor32)
            float z0[2];
#pragma unroll
            for (int j = 0; j < 2; ++j) {
                const float t = lo32 ? yp[j]     : yp[j + 2];
                const float u = lo32 ? yp[j + 2] : yp[j];
                z0[j] = t + __int_as_float(
                    __builtin_amdgcn_ds_bpermute(bpa, __float_as_int(u)));
            }
            // fold 2 -> 1 across 16-lane halves (ds_swizzle xor16)
            float z2;
            {
                const float t = b16 ? z0[1] : z0[0];
                const float u = b16 ? z0[0] : z0[1];
                z2 = t + swz_xor16(u);
            }
            // within-16 shift-reduce: lane (&15)==15 accumulates group sum
            z2 += __int_as_float(__builtin_amdgcn_update_dpp(0, __float_as_int(z2), 0x111, 0xf, 0xf, true));
            z2 += __int_as_float(__builtin_amdgcn_update_dpp(0, __float_as_int(z2), 0x112, 0xf, 0xf, true));
            z2 += __int_as_float(__builtin_amdgcn_update_dpp(0, __float_as_int(z2), 0x114, 0xf, 0xf, true));
            z2 += __int_as_float(__builtin_amdgcn_update_dpp(0, __float_as_int(z2), 0x118, 0xf, 0xf, true));
            zsel[di] = z2;
        }
        if (wl) {
            const int l = w * SEGL + s * 4 + g;
            const long row = (long)b * L_SEQ + l;
            const ushort4 zu = *(const ushort4*)&xz[row * (2 * D_INNER) + D_INNER + d0];
            ushort4 pk;
            pk.x = f2bfbits(zsel[0] * silu_f(bf2f(zu.x)));
            pk.y = f2bfbits(zsel[1] * silu_f(bf2f(zu.y)));
            pk.z = f2bfbits(zsel[2] * silu_f(bf2f(zu.z)));
            pk.w = f2bfbits(zsel[3] * silu_f(bf2f(zu.w)));
            *reinterpret_cast<ushort4*>(yb + row * D_INNER + d0) = pk;
        }
    }
}

// ---------------------------------------------------------------------------
// Flash-style cross-attention with FUSED LN2 + q-projection.
// LN2(h1) for the block's 16 rows is computed in-block (16 threads/row,
// shfl_xor width-16 reduce, bf16-rounded into LDS), then q-proj reads A
// from LDS.  Removes the ln_kernel dispatch (ln2b was attn-only).
// ---------------------------------------------------------------------------
#define QT 16
#define CK 64

__global__ __launch_bounds__(256) void attn_kernel(
    const float* __restrict__ h1, const float* __restrict__ n2a,
    const float* __restrict__ n2b,
    const bf16* __restrict__ WQb, const float* __restrict__ WQB,
    const bf16* __restrict__ kbb, const bf16* __restrict__ vbb,
    bf16* __restrict__ o)
{
    const int qt = blockIdx.x;
    const int hh = blockIdx.y;
    const int b  = blockIdx.z;
    const int t = threadIdx.x;

    __shared__ unsigned short qln[QT][256];   // LN2 rows, bf16 bits (8 KB)
    __shared__ float qs[QT][33];
    __shared__ float Ks[CK][36];
    __shared__ float Vs[CK][36];

    // ---- fused LN2: 16 threads per row, 16 f32 each, shfl width-16 -------
    {
        const int r  = t >> 4;                 // row 0..15
        const int cg = (t & 15) * 16;          // col start
        const long rb = ((long)(b * L_SEQ + qt * QT + r)) << 8;
        float xv[16];
        float s = 0.f, q = 0.f;
#pragma unroll
        for (int i = 0; i < 16; i += 4) {
            const float4 v = *(const float4*)&h1[rb + cg + i];
            xv[i] = v.x; xv[i+1] = v.y; xv[i+2] = v.z; xv[i+3] = v.w;
            s += v.x + v.y + v.z + v.w;
            q = fmaf(v.x, v.x, fmaf(v.y, v.y, fmaf(v.z, v.z, fmaf(v.w, v.w, q))));
        }
#pragma unroll
        for (int off = 8; off > 0; off >>= 1) {
            s += __shfl_xor(s, off, 16);
            q += __shfl_xor(q, off, 16);
        }
        const float mean = s * (1.f / 256.f);
        const float var = (q - 256.f * mean * mean) * (1.f / 255.f);
        const float sd = sqrtf(fmaxf(var, 0.f));
#pragma unroll
        for (int i = 0; i < 16; i += 2) {
            const int c = cg + i;
            const float o0 = n2a[c]   * (xv[i]   - mean) / (sd + 1e-6f) + n2b[c];
            const float o1 = n2a[c+1] * (xv[i+1] - mean) / (sd + 1e-6f) + n2b[c+1];
            const unsigned int pk = (unsigned)f2bfbits(o0) | ((unsigned)f2bfbits(o1) << 16);
            *(unsigned int*)&qln[r][c] = pk;
        }
    }
    __syncthreads();

    // ---- fused q: thread t computes q[row=t>>4][cols (t*2)&31 .. +1] -----
    {
        const int qr = t >> 4;
        const int c  = (t * 2) & 31;
        const bf16* ar = (const bf16*)&qln[qr][0];
        const bf16* w0 = WQb + (long)(hh * DK + c) * D_MODEL;
        const bf16* w1 = w0 + D_MODEL;
        float a0 = 0.f, a1 = 0.f;
        for (int kk = 0; kk < D_MODEL; kk += 8) {
            const short8 av = *(const short8*)(ar + kk);
            const short8 b0 = *(const short8*)(w0 + kk);
            const short8 b1 = *(const short8*)(w1 + kk);
#pragma unroll
            for (int e = 0; e < 8; ++e) {
                const float af = bf2f((unsigned short)av[e]);
                a0 = fmaf(af, bf2f((unsigned short)b0[e]), a0);
                a1 = fmaf(af, bf2f((unsigned short)b1[e]), a1);
            }
        }
        qs[qr][c]     = a0 + WQB[hh * DK + c];
        qs[qr][c + 1] = a1 + WQB[hh * DK + c + 1];
    }
    __syncthreads();

    const int lane = t & 15;
    const int qa = t >> 4;
    const int q0 = qt * QT + qa;
    const float scale = 0.17677669529663687f;
    float qr0[32];
#pragma unroll
    for (int i = 0; i < 32; ++i) qr0[i] = qs[qa][i] * scale;

    float m0 = -1e30f, l0 = 0.f, o0[32] = {};

    for (int c = 0; c < L_SEQ; c += CK) {
        __syncthreads();
        {
            const int row = t >> 2;              // 64 rows, 4 threads/row
            const int c0  = (t & 3) * 8;
            const long base = (long)(b * L_SEQ + c + row) * D_MODEL + hh * DK + c0;
            const short8 k8 = *(const short8*)(kbb + base);
            const short8 v8 = *(const short8*)(vbb + base);
            float4 f;
            f.x = bf2f((unsigned short)k8[0]); f.y = bf2f((unsigned short)k8[1]);
            f.z = bf2f((unsigned short)k8[2]); f.w = bf2f((unsigned short)k8[3]);
            *(float4*)&Ks[row][c0] = f;
            f.x = bf2f((unsigned short)k8[4]); f.y = bf2f((unsigned short)k8[5]);
            f.z = bf2f((unsigned short)k8[6]); f.w = bf2f((unsigned short)k8[7]);
            *(float4*)&Ks[row][c0 + 4] = f;
            f.x = bf2f((unsigned short)v8[0]); f.y = bf2f((unsigned short)v8[1]);
            f.z = bf2f((unsigned short)v8[2]); f.w = bf2f((unsigned short)v8[3]);
            *(float4*)&Vs[row][c0] = f;
            f.x = bf2f((unsigned short)v8[4]); f.y = bf2f((unsigned short)v8[5]);
            f.z = bf2f((unsigned short)v8[6]); f.w = bf2f((unsigned short)v8[7]);
            *(float4*)&Vs[row][c0 + 4] = f;
        }
        __syncthreads();

        float s0[4];
#pragma unroll
        for (int i = 0; i < 4; ++i) {
            const int kk = i * 16 + lane;
            float a0 = 0.f;
#pragma unroll
            for (int dd = 0; dd < 32; dd += 4) {
                const float4 kv = *(const float4*)&Ks[kk][dd];
                a0 = fmaf(qr0[dd+0], kv.x, a0); a0 = fmaf(qr0[dd+1], kv.y, a0);
                a0 = fmaf(qr0[dd+2], kv.z, a0); a0 = fmaf(qr0[dd+3], kv.w, a0);
            }
            s0[i] = a0;
        }

        float cm0 = s0[0];
#pragma unroll
        for (int i = 1; i < 4; ++i) cm0 = fmaxf(cm0, s0[i]);
#pragma unroll
        for (int off = 8; off > 0; off >>= 1)
            cm0 = fmaxf(cm0, __shfl_down(cm0, off, 16));
        cm0 = __shfl(cm0, 0, 16);

        const float nm0 = fmaxf(m0, cm0);
        const float al0 = fexp(m0 - nm0);
        l0 *= al0;
#pragma unroll
        for (int dd = 0; dd < 32; ++dd) o0[dd] *= al0;
        m0 = nm0;

        float p0[4];
#pragma unroll
        for (int i = 0; i < 4; ++i) { p0[i] = fexp(s0[i] - m0); l0 += p0[i]; }

#pragma unroll
        for (int i = 0; i < 4; ++i) {
            const int kk = i * 16 + lane;
#pragma unroll
            for (int dd = 0; dd < 32; dd += 4) {
                const float4 vv = *(const float4*)&Vs[kk][dd];
                o0[dd+0] = fmaf(p0[i], vv.x, o0[dd+0]);
                o0[dd+1] = fmaf(p0[i], vv.y, o0[dd+1]);
                o0[dd+2] = fmaf(p0[i], vv.z, o0[dd+2]);
                o0[dd+3] = fmaf(p0[i], vv.w, o0[dd+3]);
            }
        }
    }

#pragma unroll
    for (int off = 8; off > 0; off >>= 1) {
        l0 += __shfl_down(l0, off, 16);
#pragma unroll
        for (int dd = 0; dd < 32; ++dd) o0[dd] += __shfl_down(o0[dd], off, 16);
    }
    if (lane == 0) {
        const float i0 = 1.f / l0;
        bf16* op0 = o + ((long)(b * L_SEQ + q0) * D_MODEL + hh * DK);
#pragma unroll
        for (int dd = 0; dd < 32; ++dd) op0[dd] = __float2bfloat16(o0[dd] * i0);
    }
}

// ---------------------------------------------------------------------------

extern "C" void kernel_launch(void* const* d_in, const int* in_sizes, int n_in,
                              void* d_out, int out_size, void* d_ws, size_t ws_size,
                              hipStream_t stream) {
    const float* X   = (const float*)d_in[0];
    const float* MEM = (const float*)d_in[1];
    const float* CW  = (const float*)d_in[5];
    const float* CB  = (const float*)d_in[6];
    const float* DTW = (const float*)d_in[8];
    const float* DTB = (const float*)d_in[9];
    const float* ALG = (const float*)d_in[10];
    const float* DP  = (const float*)d_in[11];
    const float* N1A = (const float*)d_in[13];
    const float* N1B = (const float*)d_in[14];
    const float* N2A = (const float*)d_in[15];
    const float* N2B = (const float*)d_in[16];
    const float* N3A = (const float*)d_in[17];
    const float* N3B = (const float*)d_in[18];
    const float* WQB = (const float*)d_in[20];
    const float* WKB = (const float*)d_in[22];
    const float* WVB = (const float*)d_in[24];
    const float* WOB = (const float*)d_in[26];
    const float* W1B = (const float*)d_in[28];
    const float* W2B = (const float*)d_in[30];
    const float* INW = (const float*)d_in[4];
    const float* XPW = (const float*)d_in[7];
    const float* OPW = (const float*)d_in[12];
    const float* WQ  = (const float*)d_in[19];
    const float* WKw = (const float*)d_in[21];
    const float* WVw = (const float*)d_in[23];
    const float* WO  = (const float*)d_in[25];
    const float* W1  = (const float*)d_in[27];
    const float* W2  = (const float*)d_in[29];
    float* out = (float*)d_out;

    // ---- bf16 arena ----
    bf16* bp = (bf16*)d_ws;
    bf16* ub   = bp;  bp += (long)R_TOT * D_INNER;
    bf16* ybb  = bp;  bp += (long)R_TOT * D_INNER;
    bf16* ffab = ybb;
    bf16* xzb  = bp;  bp += (long)R_TOT * 2 * D_INNER;   // bf16 xz
    bf16* ln1b = bp;  bp += (long)R_TOT * D_MODEL;
    bf16* aob  = ln1b;
    bf16* ln3b = bp;  bp += (long)R_TOT * D_MODEL;
    bf16* kbb  = bp;  bp += (long)R_TOT * D_MODEL;       // bf16 k
    bf16* vbb  = bp;  bp += (long)R_TOT * D_MODEL;       // bf16 v
    bf16* arena = bp; bp += S_TOT;
    bf16* MEMb = arena;
    bf16* INWb = MEMb + S_MEM;
    bf16* XPWb = INWb + S_INW;
    bf16* OPWb = XPWb + S_XPW;
    bf16* WQb  = OPWb + S_OPW;
    bf16* WKb  = WQb + S_WQ;
    bf16* WVb  = WKb + S_WK;
    bf16* WOb  = WVb + S_WV;
    bf16* W1b  = WOb + S_WO;
    bf16* W2b  = W1b + S_W1;

    // ---- f32 buffers ----
    float* p = (float*)(bp + ((((long)(bp - (bf16*)d_ws)) & 1) ? 1 : 0));
    float* uT  = p;                                  p += (long)R_TOT * D_INNER;
    float* dbl = p;                                  p += (long)R_TOT * DBL_LD;
    float* h1  = p;                                  p += (long)R_TOT * D_MODEL;
    float* h2  = p;                                  p += (long)R_TOT * D_MODEL;

    const dim3 blk256(256);
    const int MT64 = R_TOT / 64;   // 16

    // 0. pack weights + memory to bf16 (x4 vectorized) + ln1 + zero h1/out/dbl
    pack_ln1<<<PACK_BLKS + R_TOT + ZERO_BLKS, blk256, 0, stream>>>(
        MEM, INW, XPW, OPW, WQ, WKw, WVw, WO, W1, W2, arena,
        X, N1A, N1B, ln1b, h1, out, dbl);

    // 1. xz = ln1 @ in_proj^T + k/v = mem @ wk/wv^T  (merged, grid (40,16))
    xz_kv_gemm<<<dim3(40, MT64), blk256, 0, stream>>>(
        ln1b, INWb, xzb, MEMb, WKb, WVb, WKB, WVB, kbb, vbb);

    // 2. conv+silu (bf16 xz) -> ub (bf16) + uT (f32 transposed)
    conv_silu_T<<<dim3(D_INNER / 64, L_SEQ / 64, B_SZ), blk256, 0, stream>>>(
        xzb, CW, CB, ub, uT);

    // 3. x_proj (split-K=4, atomics) -> dbl
    xproj_gemm<<<dim3((DBL_LD + 63) / 64, MT64, 4), blk256, 0, stream>>>(
        ub, XPWb, dbl);

    // 4. fused segmented scan + on-the-fly dt + gate epilogue -> ybb bf16
    scan_fused<<<B_SZ * D_INNER / DPB, dim3(1024), 0, stream>>>(
        uT, dbl, ALG, DTW, DTB, DP, xzb, ybb);

    // 5. h1 = X + y @ out_proj^T  (split-K=4, 256 blocks, atomic f32)
    splitk_gemm<4><<<dim3(D_MODEL / 64, MT64, 4), blk256, 0, stream>>>(
        ybb, OPWb, D_INNER, h1, D_MODEL, nullptr, X, R_TOT, D_MODEL);

    // 6. attention with fused LN2 + q-projection, bf16 k/v -> bf16
    attn_kernel<<<dim3(L_SEQ / QT, N_HEADS, B_SZ), blk256, 0, stream>>>(
        h1, N2A, N2B, WQb, WQB, kbb, vbb, aob);

    // 7. h2 = h1 + ao @ wo^T + wo_b (f32) + fused LN3 -> bf16 (K=256)
    gemm16_ln<<<R_TOT / 16, blk256, 0, stream>>>(
        aob, WOb, D_MODEL, WOB, h1, h2, N3A, N3B, ln3b);

    // 8. ffa = relu(ln3 @ w1^T + b) -> bf16
    mfma_gemm<1><<<dim3(D_FF / 64, MT64), blk256, 0, stream>>>(
        ln3b, W1b, D_MODEL, nullptr, ffab, D_FF, W1B, nullptr, R_TOT, D_FF);

    // 9. out = h2 + ffa @ w2^T + b  (split-K=4, 256 blocks, atomic f32)
    splitk_gemm<4><<<dim3(D_MODEL / 64, MT64, 4), blk256, 0, stream>>>(
        ffab, W2b, D_FF, out, D_MODEL, W2B, h2, R_TOT, D_MODEL);

    (void)in_sizes; (void)n_in; (void)out_size; (void)ws_size;
}